// Round 11
// baseline (224.336 us; speedup 1.0000x reference)
//
#include <hip/hip_runtime.h>
#include <hip/hip_bf16.h>
#include <cstddef>
#include <cstdint>

// Problem constants (fixed by reference)
#define BATCH   2
#define S_LEN   2048
#define D_MODEL 1024
#define NH      16
#define HD      64
#define MAXD    1024

// logits = scores*(1/sqrt(64)) + (scores + rel_bias)*64^-0.25
//        = scores*0.47855339 + rel_bias*0.35355339
#define SCORE_SCALE 0.47855339059327373f
#define BIAS_SCALE  0.35355339059327373f
#define FIXM 8.0f
#define LOG2E 1.4426950408889634f

typedef __attribute__((ext_vector_type(8))) short bf16x8;
typedef __attribute__((ext_vector_type(4))) short bf16x4;
typedef __attribute__((ext_vector_type(4))) float f32x4;

#if __has_builtin(__builtin_amdgcn_mfma_f32_16x16x16bf16_1k)
#define USE_1K 1
#else
#define USE_1K 0
#endif

static __device__ __forceinline__ unsigned short f2bf(float f) {
    __hip_bfloat16 h = __float2bfloat16(f);
    return *reinterpret_cast<unsigned short*>(&h);
}
static __device__ __forceinline__ float bf2f(unsigned short u) {
    union { unsigned int i; float f; } c;
    c.i = ((unsigned int)u) << 16;
    return c.f;
}

// Packed f32x2 -> bf16x2 (lo in bits [15:0]). Uses gfx950 hw v_cvt_pk_bf16_f32
// when the builtin exists (1 VALU instr vs ~10 for the sw RNE sequence).
static __device__ __forceinline__ unsigned int pk_bf16(float lo, float hi) {
#if __has_builtin(__builtin_amdgcn_cvt_pk_bf16_f32)
    auto v = __builtin_amdgcn_cvt_pk_bf16_f32(lo, hi);
    unsigned int r;
    __builtin_memcpy(&r, &v, 4);
    return r;
#else
    __hip_bfloat162 h = __float22bfloat162_rn(make_float2(lo, hi));
    return *reinterpret_cast<unsigned int*>(&h);
#endif
}

#define GLDS(gp, lp) __builtin_amdgcn_global_load_lds( \
    (const __attribute__((address_space(1))) void*)(gp), \
    (__attribute__((address_space(3))) void*)(lp), 16, 0, 0)

// ---------------------------------------------------------------------------
// prep: one launch for (a) x fp32->bf16, (b) 4 weight transpose+converts,
// (c) per-head bias table pb_t[h][rel+2047] with clamp/scales/log2e folded.
// ---------------------------------------------------------------------------
__global__ __launch_bounds__(256) void prep(
    const float* __restrict__ x,
    const float* __restrict__ Wq, const float* __restrict__ Wk,
    const float* __restrict__ Wv, const float* __restrict__ Wo,
    const float* __restrict__ pos_bias,
    unsigned short* __restrict__ xb, unsigned short* __restrict__ Wqkvt,
    unsigned short* __restrict__ Wot,
    float* __restrict__ pb_t)
{
    __shared__ float t[32][33];
    const int bx = blockIdx.x, tid = threadIdx.x;

    if (bx < 2048) {                       // ---- x convert
        const size_t i = ((size_t)bx * 256 + tid) * 8;
        const float4 a = *(const float4*)(x + i);
        const float4 b = *(const float4*)(x + i + 4);
        uint4 u;
        u.x = pk_bf16(a.x, a.y);
        u.y = pk_bf16(a.z, a.w);
        u.z = pk_bf16(b.x, b.y);
        u.w = pk_bf16(b.z, b.w);
        *(uint4*)(xb + i) = u;
    } else if (bx < 6144) {                // ---- weight transpose+convert
        const int bx2 = bx - 2048;
        const int z = bx2 >> 10, inner = bx2 & 1023;
        const int gx = inner & 31, gy = inner >> 5;
        const float* W = (z == 0) ? Wq : (z == 1) ? Wk : (z == 2) ? Wv : Wo;
        unsigned short* hi = (z < 3) ? Wqkvt + (size_t)z * 1024 * 1024 : Wot;
        const int bxx = gx * 32, byy = gy * 32;
        const int tx = tid & 31, ty = tid >> 5;
        #pragma unroll
        for (int i = 0; i < 4; i++)
            t[ty + 8 * i][tx] = W[(size_t)(byy + ty + 8 * i) * 1024 + bxx + tx];
        __syncthreads();
        #pragma unroll
        for (int i = 0; i < 4; i++) {
            const float v = t[tx][ty + 8 * i];
            const size_t o = (size_t)(bxx + ty + 8 * i) * 1024 + byy + tx;
            hi[o] = f2bf(v);
        }
    } else {                               // ---- bias table, 16 heads x 4096
        const int o0 = (bx - 6144) * 1024 + tid * 4;
        float v[4];
        #pragma unroll
        for (int j = 0; j < 4; j++) {
            const int o = o0 + j;
            const int hh = o >> 12, ii = o & 4095;
            int rel = ii - 2047;
            rel = min(max(rel, -(MAXD - 1)), MAXD - 1);
            v[j] = (BIAS_SCALE * pos_bias[(size_t)(rel + MAXD - 1) * NH + hh] - FIXM) * LOG2E;
        }
        *(float4*)&pb_t[o0] = *(const float4*)v;
    }
}

// ---------------------------------------------------------------------------
// Fused QKV GEMM: C[4096,3072] = xb @ Wqkvt^T. 128x128 tile, BK=32, m97-style.
// Col region 0->Q [B,S,D] (+bq), 1->K [B,S,D], 2->V^T [B,H,HD,S] (+bv, packed).
// ---------------------------------------------------------------------------
#define GBM 128
#define GBN 128
#define GBK 32

__global__ __launch_bounds__(256) void gemm_qkv(
    const unsigned short* __restrict__ A, const unsigned short* __restrict__ Bt,
    const float* __restrict__ bq, const float* __restrict__ bv,
    unsigned short* __restrict__ Cout)
{
    const int K = 1024;
    __shared__ __align__(16) unsigned short As[GBM][GBK];
    __shared__ __align__(16) unsigned short Bs[GBN][GBK];

    const int tid = threadIdx.x;
    const int wave = tid >> 6, lane = tid & 63;
    const int quad = lane >> 4, cl = lane & 15;
    const int wm = (wave & 1) * 64, wn = (wave >> 1) * 64;
    const int bm = blockIdx.y * GBM, bn = blockIdx.x * GBN;

    const int sr = wave * 32 + (lane >> 2);
    const int sc = (lane & 3) * 8;
    const unsigned short* aS0 = A  + (size_t)(bm + sr) * K + sc;
    const unsigned short* aS1 = aS0 + (size_t)16 * K;
    const unsigned short* bS0 = Bt + (size_t)(bn + sr) * K + sc;
    const unsigned short* bS1 = bS0 + (size_t)16 * K;
    unsigned short* aD0 = &As[wave * 32][0];
    unsigned short* aD1 = &As[wave * 32 + 16][0];
    unsigned short* bD0 = &Bs[wave * 32][0];
    unsigned short* bD1 = &Bs[wave * 32 + 16][0];

    f32x4 acc[4][4];
    #pragma unroll
    for (int mi = 0; mi < 4; mi++)
        #pragma unroll
        for (int ni = 0; ni < 4; ni++)
            #pragma unroll
            for (int r = 0; r < 4; r++) acc[mi][ni][r] = 0.f;

    for (int k0 = 0; k0 < K; k0 += GBK) {
        __syncthreads();
        GLDS(aS0, aD0); GLDS(aS1, aD1);
        GLDS(bS0, bD0); GLDS(bS1, bD1);
        aS0 += GBK; aS1 += GBK; bS0 += GBK; bS1 += GBK;
        __syncthreads();

        bf16x8 af[4], bf[4];
        #pragma unroll
        for (int mi = 0; mi < 4; mi++)
            af[mi] = *(const bf16x8*)&As[wm + mi * 16 + cl][quad * 8];
        #pragma unroll
        for (int ni = 0; ni < 4; ni++)
            bf[ni] = *(const bf16x8*)&Bs[wn + ni * 16 + cl][quad * 8];
        #pragma unroll
        for (int mi = 0; mi < 4; mi++)
            #pragma unroll
            for (int ni = 0; ni < 4; ni++)
                acc[mi][ni] = __builtin_amdgcn_mfma_f32_16x16x32_bf16(
                    af[mi], bf[ni], acc[mi][ni], 0, 0, 0);
    }

    #pragma unroll
    for (int ni = 0; ni < 4; ni++) {
        const int coln = bn + wn + ni * 16 + cl;
        const int region = coln >> 10, c = coln & 1023;
        const float bs = (region == 0) ? bq[c] : (region == 2) ? bv[c] : 0.f;
        #pragma unroll
        for (int mi = 0; mi < 4; mi++) {
            const int row0 = bm + wm + mi * 16 + quad * 4;
            if (region == 2) {
                const int hh = c >> 6, d = c & 63;
                const int bb = row0 >> 11, s0 = row0 & 2047;
                uint2 w;
                w.x = pk_bf16(acc[mi][ni][0] + bs, acc[mi][ni][1] + bs);
                w.y = pk_bf16(acc[mi][ni][2] + bs, acc[mi][ni][3] + bs);
                unsigned short* dst = Cout + (size_t)8 * 1024 * 1024
                    + (((size_t)bb * NH + hh) * HD + d) * S_LEN + s0;
                *(uint2*)dst = w;
            } else {
                unsigned short* dst = Cout + (size_t)region * 4 * 1024 * 1024;
                #pragma unroll
                for (int r = 0; r < 4; r++)
                    dst[(size_t)(row0 + r) * 1024 + c] = f2bf(acc[mi][ni][r] + bs);
            }
        }
    }
}

// ---------------------------------------------------------------------------
// MFMA flash attention v5 (R10 structure): TQB=64, single-buffer GLDS staging
// with the proven m97 2-barrier pattern. LDS = 16384 B -> wave-capped 8
// blocks/CU. XOR-swizzled unpadded LDS; register-resident P via mfma_16x16x16
// PV; lsum via ones-A MFMA; bias from precomputed global table.
// R11: hw v_cvt_pk_bf16_f32 for the softmax P-pack (the VALU hot spot).
// ---------------------------------------------------------------------------
#define TQB 64
#define TKB 64

__global__ __launch_bounds__(256) void attn_mfma(
    const unsigned short* __restrict__ Q, const unsigned short* __restrict__ K,
    const unsigned short* __restrict__ VT, const float* __restrict__ pb_t,
    unsigned short* __restrict__ O)
{
    const int qt = blockIdx.x, h = blockIdx.y, b = blockIdx.z;
    const int tid  = threadIdx.x;
    const int wave = tid >> 6, lane = tid & 63;
    const int quad = lane >> 4, col = lane & 15;
    const int qbase = qt * TQB;
    const int qw = qbase + wave * 16;

    __shared__ __align__(16) unsigned short Ks[TKB][HD];   // 8192 B
    __shared__ __align__(16) unsigned short Vs[HD][TKB];   // 8192 B
#if !USE_1K
    __shared__ __align__(16) unsigned short Ps[4][16][TKB];
#endif

    bf16x8 qf[2];
    {
        const unsigned short* qp =
            &Q[((size_t)(b * S_LEN) + qw + col) * D_MODEL + h * HD + quad * 8];
        qf[0] = *(const bf16x8*)qp;
        qf[1] = *(const bf16x8*)(qp + 32);
    }

    f32x4 accO[4];
    #pragma unroll
    for (int nb = 0; nb < 4; nb++)
        #pragma unroll
        for (int r = 0; r < 4; r++) accO[nb][r] = 0.f;
#if USE_1K
    f32x4 accL;
    #pragma unroll
    for (int r = 0; r < 4; r++) accL[r] = 0.f;
    const bf16x4 vone = {(short)16256, (short)16256, (short)16256, (short)16256}; // bf16 1.0
#else
    float lsum = 0.f;
#endif

    // GLDS staging: slot s=i*256+tid holds (row=s>>3, chunk (s&7)^(row&7)).
    const int s0 = tid, s1 = 256 + tid;
    const int kr0 = s0 >> 3, kj0 = (s0 & 7) ^ (kr0 & 7);
    const int kr1 = s1 >> 3, kj1 = (s1 & 7) ^ (kr1 & 7);
    const unsigned short* kS0 = K + ((size_t)(b * S_LEN) + kr0) * D_MODEL + h * HD + kj0 * 8;
    const unsigned short* kS1 = K + ((size_t)(b * S_LEN) + kr1) * D_MODEL + h * HD + kj1 * 8;
    const size_t vbase = ((size_t)(b * NH + h) * HD) * S_LEN;
    const unsigned short* vS0 = VT + vbase + (size_t)kr0 * S_LEN + kj0 * 8;
    const unsigned short* vS1 = VT + vbase + (size_t)kr1 * S_LEN + kj1 * 8;
    unsigned short* kD = &Ks[0][0] + wave * 512;   // wave-uniform LDS bases
    unsigned short* vD = &Vs[0][0] + wave * 512;

    const float* pbh = pb_t + h * 4096;
    const float* pb_lane = pbh + (qbase + wave * 16 + col - quad * 4 + 2047);
    const float SC2 = SCORE_SCALE * LOG2E;
    const int jsw = col & 7;   // swizzle key for this lane's rows

    for (int kb = 0; kb < S_LEN; kb += TKB) {
        __syncthreads();   // prior tile's LDS reads complete before overwrite
        GLDS(kS0, kD); GLDS(kS1, kD + 2048);
        GLDS(vS0, vD); GLDS(vS1, vD + 2048);
        kS0 += (size_t)TKB * D_MODEL; kS1 += (size_t)TKB * D_MODEL;
        vS0 += TKB; vS1 += TKB;

        // bias loads overlap the GLDS drain (global, off the LDS pipe)
        float bias_r[16];
        #pragma unroll
        for (int nb = 0; nb < 4; nb++)
            #pragma unroll
            for (int r = 0; r < 4; r++)
                bias_r[nb * 4 + r] = pb_lane[-(nb * 16 + r)];

        __syncthreads();   // barrier drains vmcnt -> glds data visible

        // QK^T: C[key=nb*16+quad*4+r][q=col]
        f32x4 accS[4];
        #pragma unroll
        for (int nb = 0; nb < 4; nb++)
            #pragma unroll
            for (int r = 0; r < 4; r++) accS[nb][r] = 0.f;
        #pragma unroll
        for (int kk = 0; kk < 2; kk++)
            #pragma unroll
            for (int nb = 0; nb < 4; nb++) {
                const bf16x8 kf = *(const bf16x8*)
                    &Ks[nb * 16 + col][((kk * 4 + quad) ^ jsw) * 8];
                accS[nb] = __builtin_amdgcn_mfma_f32_16x16x32_bf16(kf, qf[kk], accS[nb], 0, 0, 0);
            }

        // softmax: p = exp2(score*SC2 + bias2); hw-packed bf16 pairs
#if USE_1K
        bf16x4 pf[4];
#endif
        #pragma unroll
        for (int nb = 0; nb < 4; nb++) {
            float pr[4];
            #pragma unroll
            for (int r = 0; r < 4; r++)
                pr[r] = __builtin_amdgcn_exp2f(fmaf(accS[nb][r], SC2, bias_r[nb * 4 + r]));
            uint2 w;
            w.x = pk_bf16(pr[0], pr[1]);
            w.y = pk_bf16(pr[2], pr[3]);
#if USE_1K
            union { uint2 u; bf16x4 v; } cv;
            cv.u = w;
            pf[nb] = cv.v;
            // lsum: ones-A MFMA sums pf over k (across quads) -> accL[*][q=col]
            accL = __builtin_amdgcn_mfma_f32_16x16x16bf16_1k(vone, pf[nb], accL, 0, 0, 0);
#else
            #pragma unroll
            for (int r = 0; r < 4; r++) lsum += pr[r];
            const int jp = ((nb * 2 + (quad >> 1)) ^ jsw) * 8 + (quad & 1) * 4;
            *(uint2*)&Ps[wave][col][jp] = w;
#endif
        }

        // PV
#if USE_1K
        // O^T[d=nb*16+quad*4+r][q=col] += V^T[d][key] * P^T[key][q]
        #pragma unroll
        for (int s = 0; s < 4; s++) {
            #pragma unroll
            for (int nb = 0; nb < 4; nb++) {
                const bf16x4 vf = *(const bf16x4*)
                    &Vs[nb * 16 + col][(((2 * s + (quad >> 1)) ^ jsw) * 8) + (quad & 1) * 4];
                accO[nb] = __builtin_amdgcn_mfma_f32_16x16x16bf16_1k(vf, pf[s], accO[nb], 0, 0, 0);
            }
        }
#else
        #pragma unroll
        for (int kk = 0; kk < 2; kk++) {
            const bf16x8 af = *(const bf16x8*)
                &Ps[wave][col][((kk * 4 + quad) ^ jsw) * 8];
            #pragma unroll
            for (int nb = 0; nb < 4; nb++) {
                const bf16x8 vf = *(const bf16x8*)
                    &Vs[nb * 16 + col][((kk * 4 + quad) ^ jsw) * 8];
                accO[nb] = __builtin_amdgcn_mfma_f32_16x16x32_bf16(af, vf, accO[nb], 0, 0, 0);
            }
        }
#endif
        pb_lane -= TKB;
    }

#if USE_1K
    // accL rows are all identical = full l for q=col (summed across quads by MFMA)
    const float inv = 1.0f / accL[0];
    const size_t row = (size_t)(b * S_LEN) + qw + col;
    #pragma unroll
    for (int nb = 0; nb < 4; nb++) {
        uint2 w;
        w.x = pk_bf16(accO[nb][0] * inv, accO[nb][1] * inv);
        w.y = pk_bf16(accO[nb][2] * inv, accO[nb][3] * inv);
        *(uint2*)&O[row * D_MODEL + h * HD + nb * 16 + quad * 4] = w;
    }
#else
    lsum += __shfl_xor(lsum, 16);
    lsum += __shfl_xor(lsum, 32);
    #pragma unroll
    for (int r = 0; r < 4; r++) {
        const float inv = 1.0f / __shfl(lsum, quad * 4 + r);
        const size_t row = (size_t)(b * S_LEN) + qw + quad * 4 + r;
        #pragma unroll
        for (int nb = 0; nb < 4; nb++)
            O[row * D_MODEL + h * HD + nb * 16 + col] = f2bf(accO[nb][r] * inv);
    }
#endif
}

// ---------------------------------------------------------------------------
// Output projection: out[4096,1024] = Ab @ Wot^T + bo, fp32 out.
// 64x128 tile (512 blocks), BK=32, single bf16 B.
// ---------------------------------------------------------------------------
#define OBM 64
#define OBN 128

__global__ __launch_bounds__(256) void gemm_out(
    const unsigned short* __restrict__ A, const unsigned short* __restrict__ Bt,
    const float* __restrict__ bias, float* __restrict__ Cout)
{
    const int N = 1024, Kd = 1024;
    __shared__ __align__(16) unsigned short As[OBM][GBK];
    __shared__ __align__(16) unsigned short Bs[OBN][GBK];

    const int tid = threadIdx.x;
    const int wave = tid >> 6, lane = tid & 63;
    const int quad = lane >> 4, cl = lane & 15;
    const int wm = (wave & 1) * 32, wn = (wave >> 1) * 64;
    const int bm = blockIdx.y * OBM, bn = blockIdx.x * OBN;

    const int ar = tid >> 2, ac = (tid & 3) * 8;
    const unsigned short* aS = A + (size_t)(bm + ar) * Kd + ac;
    const unsigned short* hS0 = Bt + (size_t)(bn + ar) * Kd + ac;
    const unsigned short* hS1 = hS0 + (size_t)64 * Kd;
    unsigned short* aD  = &As[0][0] + wave * 512;
    unsigned short* hD0 = &Bs[0][0] + wave * 512;
    unsigned short* hD1 = hD0 + 2048;

    f32x4 acc[2][4];
    #pragma unroll
    for (int mi = 0; mi < 2; mi++)
        #pragma unroll
        for (int ni = 0; ni < 4; ni++)
            #pragma unroll
            for (int r = 0; r < 4; r++) acc[mi][ni][r] = 0.f;

    for (int k0 = 0; k0 < Kd; k0 += GBK) {
        __syncthreads();
        GLDS(aS, aD);
        GLDS(hS0, hD0); GLDS(hS1, hD1);
        aS += GBK; hS0 += GBK; hS1 += GBK;
        __syncthreads();

        bf16x8 af[2], bh[4];
        #pragma unroll
        for (int mi = 0; mi < 2; mi++)
            af[mi] = *(const bf16x8*)&As[wm + mi * 16 + cl][quad * 8];
        #pragma unroll
        for (int ni = 0; ni < 4; ni++)
            bh[ni] = *(const bf16x8*)&Bs[wn + ni * 16 + cl][quad * 8];
        #pragma unroll
        for (int mi = 0; mi < 2; mi++)
            #pragma unroll
            for (int ni = 0; ni < 4; ni++)
                acc[mi][ni] = __builtin_amdgcn_mfma_f32_16x16x32_bf16(
                    af[mi], bh[ni], acc[mi][ni], 0, 0, 0);
    }

    #pragma unroll
    for (int ni = 0; ni < 4; ni++) {
        const int coln = bn + wn + ni * 16 + cl;
        const float bs = bias[coln];
        #pragma unroll
        for (int mi = 0; mi < 2; mi++) {
            const int row0 = bm + wm + mi * 16 + quad * 4;
            #pragma unroll
            for (int r = 0; r < 4; r++)
                Cout[(size_t)(row0 + r) * N + coln] = acc[mi][ni][r] + bs;
        }
    }
}

// ---------------------------------------------------------------------------
extern "C" void kernel_launch(void* const* d_in, const int* in_sizes, int n_in,
                              void* d_out, int out_size, void* d_ws, size_t ws_size,
                              hipStream_t stream)
{
    const float* x        = (const float*)d_in[0];
    const float* Wq       = (const float*)d_in[1];
    const float* bq       = (const float*)d_in[2];
    const float* Wk       = (const float*)d_in[3];
    const float* Wv       = (const float*)d_in[4];
    const float* bv       = (const float*)d_in[5];
    const float* Wo       = (const float*)d_in[6];
    const float* bo       = (const float*)d_in[7];
    const float* pos_bias = (const float*)d_in[8];
    float* out = (float*)d_out;

    const size_t ELEMS  = (size_t)BATCH * S_LEN * D_MODEL;  // 4 Mi
    const size_t WELEMS = (size_t)D_MODEL * D_MODEL;        // 1 Mi
    unsigned short* xb     = (unsigned short*)d_ws;
    unsigned short* Wqkvt  = xb + ELEMS;                    // [3072][1024]
    unsigned short* Wot    = Wqkvt + 3 * WELEMS;
    unsigned short* QKV    = Wot + WELEMS;                  // Qb | Kb | VTb
    unsigned short* Qb     = QKV;
    unsigned short* Kb     = Qb + ELEMS;
    unsigned short* VTb    = Kb + ELEMS;                    // [B,H,HD,S]
    unsigned short* Ab     = VTb + ELEMS;                   // attn out bf16 [B,S,D]
    float* pb_t            = (float*)(Ab + ELEMS);          // [NH][4096]

    prep<<<6208, 256, 0, stream>>>(x, Wq, Wk, Wv, Wo, pos_bias,
                                   xb, Wqkvt, Wot, pb_t);

    gemm_qkv<<<dim3(3072 / GBN, 4096 / GBM), 256, 0, stream>>>(
        xb, Wqkvt, bq, bv, QKV);

    attn_mfma<<<dim3(S_LEN / TQB, NH, BATCH), 256, 0, stream>>>(
        Qb, Kb, VTb, pb_t, Ab);

    gemm_out<<<dim3(1024 / OBN, 4096 / OBM), 256, 0, stream>>>(
        Ab, Wot, bo, out);
}